// Round 16
// baseline (1200.297 us; speedup 1.0000x reference)
//
#include <hip/hip_runtime.h>

typedef _Float16 half8 __attribute__((ext_vector_type(8)));
typedef _Float16 half4 __attribute__((ext_vector_type(4)));
typedef float f32x4 __attribute__((ext_vector_type(4)));

__device__ __forceinline__ void gload_lds16(const void* g, void* l) {
  __builtin_amdgcn_global_load_lds((const __attribute__((address_space(1))) void*)g,
                                   (__attribute__((address_space(3))) void*)l, 16, 0, 0);
}

// ---------------- BN partial sums: grid 128 = (seg<<4 | c) ----------------
__global__ __launch_bounds__(256) void k_bn_partial(const float* __restrict__ x,
                                                    float* __restrict__ part) {
  const int c = blockIdx.x & 15;
  const int seg = blockIdx.x >> 4;
  const int t = threadIdx.x;
  float s = 0.f, s2 = 0.f;
  for (int b = 0; b < 32; ++b) {
    const float* row = x + (size_t)(b * 16 + c) * 4000 + seg * 500;
    for (int v = t; v < 500; v += 256) {
      float val = row[v];
      s += val;
      s2 += val * val;
    }
  }
#pragma unroll
  for (int off = 32; off > 0; off >>= 1) {
    s += __shfl_down(s, off);
    s2 += __shfl_down(s2, off);
  }
  __shared__ float rs_[4], rs2_[4];
  if ((t & 63) == 0) { rs_[t >> 6] = s; rs2_[t >> 6] = s2; }
  __syncthreads();
  if (t == 0) {
    part[c * 8 + seg] = rs_[0] + rs_[1] + rs_[2] + rs_[3];
    part[128 + c * 8 + seg] = rs2_[0] + rs2_[1] + rs2_[2] + rs2_[3];
  }
}

// ---------------- BN finalize ----------------
__global__ void k_bn_final(const float* __restrict__ part, float* __restrict__ musig) {
  const int c = threadIdx.x;
  if (c < 16) {
    float S = 0.f, S2 = 0.f;
#pragma unroll
    for (int seg = 0; seg < 8; ++seg) {
      S += part[c * 8 + seg];
      S2 += part[128 + c * 8 + seg];
    }
    const float inv = 1.f / 128000.f;
    float mu = S * inv;
    float var = S2 * inv - mu * mu;
    musig[c] = mu;
    musig[16 + c] = rsqrtf(var + 1e-5f);
  }
}

// ---------------- build x0 (normalized, permuted, transposed, scaled 1/16) ----------------
__global__ __launch_bounds__(256) void k_build_x0(const float* __restrict__ x,
                                                  const int* __restrict__ perm,
                                                  const float* __restrict__ musig,
                                                  _Float16* __restrict__ X0) {
  const int idx = blockIdx.x * 256 + threadIdx.x;
  const int v = idx & 4095;
  const int m = idx >> 12;
  const int b = m & 31;
  const int c = m >> 5;
  const int pv = perm[v];
  float val = 0.f;
  if (pv < 4000)
    val = (x[((size_t)(b * 16 + c)) * 4000 + pv] - musig[c]) * musig[16 + c] * 0.0625f;
  X0[idx] = (_Float16)val;
}

// ---------------- f32 -> f16 convert ----------------
__global__ __launch_bounds__(256) void k_cvt_f16(const float* __restrict__ s,
                                                 _Float16* __restrict__ d, int n) {
  const int i = (blockIdx.x * 256 + threadIdx.x) * 4;
  if (i >= n) return;
  f32x4 v = *(const f32x4*)(s + i);
  half4 h;
  h[0] = (_Float16)v[0]; h[1] = (_Float16)v[1];
  h[2] = (_Float16)v[2]; h[3] = (_Float16)v[3];
  *(half4*)(d + i) = h;
}

// ---------------- zero fill ----------------
__global__ __launch_bounds__(256) void k_zero(_Float16* __restrict__ p, int n8) {
  const int i = blockIdx.x * 256 + threadIdx.x;
  if (i < n8) *(half8*)(p + (size_t)i * 8) = half8{};
}

// ---------------- W permute+pad: Wp[f][k*CS + c] = W[f][c*25 + k] ----------------
__global__ __launch_bounds__(256) void k_prep_w(const float* __restrict__ W,
                                                _Float16* __restrict__ Wp,
                                                int F, int shiftC, int kround) {
  const int idx = blockIdx.x * 256 + threadIdx.x;
  const int CS = 1 << shiftC;
  const int KPtot = kround * CS;
  if (idx >= F * KPtot) return;
  const int f = idx / KPtot;
  const int rem = idx - f * KPtot;
  const int k = rem >> shiftC;
  const int c = rem & (CS - 1);
  float v = 0.f;
  if (k < 25) v = W[(size_t)f * (CS * 25) + c * 25 + k];
  Wp[idx] = (_Float16)v;
}

// ---------------- Chebyshev full-K fused GEMM (both convs) ----------------
// Xout[m][v] = alpha * sum_u Xprev[m][u]*L[v][u] - beta*Xm2[m][v]
// Tile 64m x 64v, BK=64. 256 thr = 4 waves (2x2), wave 32x32 (2x2 frags).
// 3-buf LDS (48KB) -> 2 blocks/CU, 2-ahead staging, counted vmcnt(4), one
// phase per K-tile, fused epilogue. V/NT runtime: conv1 V=4096 NT=64 grid(64,8);
// conv2 V=1024 NT=16 grid(16,32). bid%8 = bx%8 and by-stride 64%8==0 => all
// by-consumers of a B-slice co-XCD: per-XCD B footprint 4MB (L2), A 4MB (L2/L3).
// No split-K: no partial planes, no reduce kernel, fp32 accum end-to-end.
__global__ __launch_bounds__(256, 2) void k_chebf(const _Float16* __restrict__ Xprev,
                                                  const _Float16* __restrict__ Lm,
                                                  const _Float16* __restrict__ Xm2,
                                                  _Float16* __restrict__ Xout,
                                                  int V, int NT, float alpha, float beta) {
  __shared__ _Float16 lds[3][8192];  // [buf][A:64x64 (8KB) | B:64x64 (8KB)]
  const int t = threadIdx.x;
  const int lane = t & 63;
  const int ln = lane & 15;
  const int g = lane >> 4;
  const int g16 = g << 4;
  const int w = t >> 6;
  const int wm = w >> 1, wn = w & 1;
  const int v0 = blockIdx.x * 64;
  const int m0 = blockIdx.y * 64;
  const size_t rs = (size_t)V * 2;

  const char* Ag = (const char*)Xprev + (size_t)m0 * rs;
  const char* Bg = (const char*)Lm + (size_t)v0 * rs;

  f32x4 acc[2][2] = {};

  auto stageHalf = [&](int buf, int tt, int half) {  // 2 gload_lds / thread
    const char* src = (half == 0) ? Ag : Bg;
    char* dst0 = (char*)&lds[buf][0] + half * 8192;
#pragma unroll
    for (int j = 0; j < 2; ++j) {
      const int idx = j * 256 + t;
      const int row = idx >> 3, c8 = idx & 7;
      gload_lds16(src + (size_t)row * rs + tt * 128 + ((c8 ^ (row & 7)) << 4),
                  dst0 + idx * 16);
    }
  };

  stageHalf(0, 0, 0); stageHalf(0, 0, 1);
  stageHalf(1, 1, 0); stageHalf(1, 1, 1);
  asm volatile("s_waitcnt vmcnt(4)" ::: "memory");
  asm volatile("s_barrier" ::: "memory");

  for (int tt = 0; tt < NT; ++tt) {
    const int cur = tt % 3;
    const int nxt = (tt + 2) % 3;
    const char* A = (const char*)&lds[cur][0];
    const char* B = A + 8192;
    half8 a[2][2], b[2][2];
#pragma unroll
    for (int kk = 0; kk < 2; ++kk) {
#pragma unroll
      for (int mi = 0; mi < 2; ++mi) {
        const int ar = wm * 32 + mi * 16 + ln;
        a[kk][mi] = *(const half8*)(A + ar * 128 + ((kk * 64 + g16) ^ ((ar & 7) << 4)));
      }
#pragma unroll
      for (int ni = 0; ni < 2; ++ni) {
        const int br = wn * 32 + ni * 16 + ln;
        b[kk][ni] = *(const half8*)(B + br * 128 + ((kk * 64 + g16) ^ ((br & 7) << 4)));
      }
    }
    if (tt + 2 < NT) {
      stageHalf(nxt, tt + 2, 0);
      stageHalf(nxt, tt + 2, 1);
      asm volatile("s_waitcnt vmcnt(4)" ::: "memory");  // T+1 landed, T+2 in flight
    } else {
      asm volatile("s_waitcnt vmcnt(0)" ::: "memory");
    }
    asm volatile("s_barrier" ::: "memory");
    asm volatile("s_waitcnt lgkmcnt(0)" ::: "memory");
    __builtin_amdgcn_sched_barrier(0);
    __builtin_amdgcn_s_setprio(1);
#pragma unroll
    for (int kk = 0; kk < 2; ++kk)
#pragma unroll
      for (int mi = 0; mi < 2; ++mi)
#pragma unroll
        for (int ni = 0; ni < 2; ++ni)
          acc[mi][ni] = __builtin_amdgcn_mfma_f32_16x16x32_f16(a[kk][mi], b[kk][ni],
                                                               acc[mi][ni], 0, 0, 0);
    __builtin_amdgcn_s_setprio(0);
    asm volatile("s_barrier" ::: "memory");
  }

  // fused epilogue: Xout = alpha*acc - beta*Xm2
#pragma unroll
  for (int mi = 0; mi < 2; ++mi) {
#pragma unroll
    for (int ni = 0; ni < 2; ++ni) {
      const int vv = v0 + wn * 32 + ni * 16 + ln;
      const int mmb = m0 + wm * 32 + mi * 16 + g * 4;
#pragma unroll
      for (int r = 0; r < 4; ++r) {
        const size_t idx = (size_t)(mmb + r) * V + vv;
        float val = alpha * acc[mi][ni][r];
        if (beta != 0.f) val -= (float)Xm2[idx];
        Xout[idx] = (_Float16)val;
      }
    }
  }
}

// ---------------- Dense projection GEMM v2 (R15) + fused maxpool4 ----------------
template <int FT, int MODE>
__global__ __launch_bounds__(256, 2) void k_dense(const _Float16* __restrict__ Wp,
                                                  const _Float16* __restrict__ XS,
                                                  const float* __restrict__ bias,
                                                  void* __restrict__ outp,
                                                  int Vv, int shiftC, int nsteps,
                                                  int k0plane, float ascale, float bscale) {
  __shared__ _Float16 Alds[2][FT * 64];
  __shared__ _Float16 Blds[2][64 * 64];
  const int t = threadIdx.x;
  const int lane = t & 63;
  const int ln = lane & 15;
  const int g = lane >> 4;
  const int w = t >> 6;
  const int wf = w >> 1, wn = w & 1;
  const int f0w = wf * (FT / 2);
  const int n0w = wn * 32;
  const int n0 = blockIdx.x * 64;
  const int b = n0 / Vv;
  const int vb = n0 % Vv;
  const int Kp = nsteps * 64;
  const int cmask = (1 << shiftC) - 1;
  const size_t plane = 2097152;
  constexpr int NM = FT / 32;

  f32x4 acc[NM][2] = {};

  auto stageA = [&](int buf, int s) {
    const int q0 = s * 64;
    char* A = (char*)&Alds[buf][0];
#pragma unroll
    for (int j = 0; j < FT / 32; ++j) {
      const int ch = j * 256 + t;
      const int f = ch >> 3, c8 = ch & 7;
      gload_lds16((const char*)Wp + ((size_t)f * Kp + q0) * 2 + ((c8 ^ (f & 7)) << 4),
                  A + ch * 16);
    }
  };
  auto loadB = [&](int s, half8* r) {
    const int q0 = s * 64;
#pragma unroll
    for (int j = 0; j < 2; ++j) {
      const int idx = j * 256 + t;
      const int q = idx >> 3, n8 = idx & 7;
      const int qq = q0 + q;
      int k = qq >> shiftC;
      const int c = qq & cmask;
      if (k == 0) k = k0plane;
      r[j] = *(const half8*)(XS + (size_t)k * plane + (size_t)(c * 32 + b) * Vv + vb + n8 * 8);
    }
  };
  auto writeB = [&](int buf, const half8* r) {
#pragma unroll
    for (int j = 0; j < 2; ++j) {
      const int idx = j * 256 + t;
      const int q = idx >> 3, n8 = idx & 7;
#pragma unroll
      for (int e = 0; e < 8; ++e) {
        const int n = n8 * 8 + e;
        Blds[buf][n * 64 + ((((q >> 3) ^ (n >> 3) ^ (n & 7))) << 3) + (q & 7)] = r[j][e];
      }
    }
  };

  half8 rb[2];
  stageA(0, 0);
  loadB(0, rb);
  writeB(0, rb);
  asm volatile("s_waitcnt vmcnt(0)" ::: "memory");
  __syncthreads();

  for (int s = 0; s < nsteps; ++s) {
    const int cur = s & 1;
    const bool more = (s + 1 < nsteps);
    if (more) {
      stageA(cur ^ 1, s + 1);
      loadB(s + 1, rb);
    }
    const _Float16* A = &Alds[cur][0];
    const _Float16* B = &Blds[cur][0];
#pragma unroll
    for (int kk = 0; kk < 2; ++kk) {
      half8 af[NM], bf[2];
#pragma unroll
      for (int mi = 0; mi < NM; ++mi) {
        const int fr = f0w + mi * 16 + ln;
        af[mi] = *(const half8*)((const char*)A + fr * 128 +
                                 ((kk * 64 + g * 16) ^ ((fr & 7) << 4)));
      }
#pragma unroll
      for (int ni = 0; ni < 2; ++ni) {
        const int n = n0w + ni * 16 + ln;
        bf[ni] = *(const half8*)((const char*)B + n * 128 +
                                 ((((kk * 4 + g) ^ (n >> 3) ^ (n & 7))) << 4));
      }
#pragma unroll
      for (int mi = 0; mi < NM; ++mi)
#pragma unroll
        for (int ni = 0; ni < 2; ++ni)
          acc[mi][ni] = __builtin_amdgcn_mfma_f32_16x16x32_f16(af[mi], bf[ni], acc[mi][ni], 0, 0, 0);
    }
    if (more) {
      writeB(cur ^ 1, rb);
      asm volatile("s_waitcnt vmcnt(0)" ::: "memory");
      __syncthreads();
    }
  }

  const bool writer = (lane & 3) == 0;
#pragma unroll
  for (int mi = 0; mi < NM; ++mi) {
#pragma unroll
    for (int ni = 0; ni < 2; ++ni) {
#pragma unroll
      for (int r = 0; r < 4; ++r) {
        const int f = f0w + mi * 16 + g * 4 + r;
        const int v = vb + n0w + ni * 16 + ln;
        float val = fmaxf(ascale * acc[mi][ni][r] + bscale * bias[f], 0.f);
        val = fmaxf(val, __shfl_xor(val, 1));
        val = fmaxf(val, __shfl_xor(val, 2));
        if (writer) {
          if constexpr (MODE == 1) {
            _Float16* Xp = (_Float16*)outp;
            Xp[(size_t)(f * 32 + b) * 1024 + (v >> 2)] = (_Float16)(val * 0.015625f);
          } else {
            float* p2o = (float*)outp;
            p2o[(size_t)b * 32768 + f * 256 + (v >> 2)] = val;
          }
        }
      }
    }
  }
}

// ---------------- FC pass 1 ----------------
__global__ __launch_bounds__(256) void k_fc_part(const float* __restrict__ p2,
                                                 const float* __restrict__ Wfc,
                                                 float* __restrict__ partF) {
  const int b = blockIdx.x >> 3;
  const int seg = blockIdx.x & 7;
  const int t = threadIdx.x;
  const int lane = t & 63;
  const int w = t >> 6;
  const int base = seg * 4096;
  float acc[10];
#pragma unroll
  for (int o = 0; o < 10; ++o) acc[o] = 0.f;
  const float* pb = p2 + (size_t)b * 32768 + base;
  for (int i = t; i < 4096; i += 256) {
    float p = pb[i];
#pragma unroll
    for (int o = 0; o < 10; ++o) acc[o] += p * Wfc[(size_t)o * 32768 + base + i];
  }
#pragma unroll
  for (int off = 32; off > 0; off >>= 1)
#pragma unroll
    for (int o = 0; o < 10; ++o) acc[o] += __shfl_down(acc[o], off);
  __shared__ float rws[10][4];
  if (lane == 0) {
#pragma unroll
    for (int o = 0; o < 10; ++o) rws[o][w] = acc[o];
  }
  __syncthreads();
  if (t < 10) partF[blockIdx.x * 10 + t] =
      rws[t][0] + rws[t][1] + rws[t][2] + rws[t][3];
}

// ---------------- FC pass 2 ----------------
__global__ void k_fc_final(const float* __restrict__ partF,
                           const float* __restrict__ bfc,
                           float* __restrict__ out) {
  const int t = threadIdx.x;
  if (t < 320) {
    const int b = t / 10, o = t - b * 10;
    float s = 0.f;
#pragma unroll
    for (int seg = 0; seg < 8; ++seg) s += partF[(b * 8 + seg) * 10 + o];
    out[b * 10 + o] = 64.f * s + bfc[o];
  }
}

extern "C" void kernel_launch(void* const* d_in, const int* in_sizes, int n_in,
                              void* d_out, int out_size, void* d_ws, size_t ws_size,
                              hipStream_t stream) {
  (void)in_sizes; (void)n_in; (void)out_size; (void)ws_size;
  const float* x = (const float*)d_in[0];
  const int* perm = (const int*)d_in[1];
  const float* L1 = (const float*)d_in[2];
  const float* L2 = (const float*)d_in[3];
  const float* W1 = (const float*)d_in[4];
  const float* b1 = (const float*)d_in[5];
  const float* W2 = (const float*)d_in[6];
  const float* b2 = (const float*)d_in[7];
  const float* Wfc = (const float*)d_in[8];
  const float* bfc = (const float*)d_in[9];
  float* out = (float*)d_out;

  char* ws = (char*)d_ws;
  size_t off = 0;
  auto alloc = [&](size_t bytes) {
    char* p = ws + off;
    off += (bytes + 255) & ~(size_t)255;
    return p;
  };
  _Float16* L1h = (_Float16*)alloc(16777216ull * 2);
  _Float16* L2h = (_Float16*)alloc(1048576ull * 2);
  _Float16* W1p = (_Float16*)alloc(64ull * 448 * 2);
  _Float16* W2p = (_Float16*)alloc(128ull * 1664 * 2);
  float* part = (float*)alloc(256 * 4);
  float* musig = (float*)alloc(32 * 4);
  float* partF = (float*)alloc(2560 * 4);
  _Float16* XS = (_Float16*)alloc(29ull * 2097152 * 2);   // 25 states + 3 zero + 1 pooled
  float* p2 = (float*)alloc(32ull * 128 * 256 * 4);

  const size_t plane = 2097152;

  k_cvt_f16<<<16384, 256, 0, stream>>>(L1, L1h, 16777216);
  k_cvt_f16<<<1024, 256, 0, stream>>>(L2, L2h, 1048576);
  k_prep_w<<<112, 256, 0, stream>>>(W1, W1p, 64, 4, 28);
  k_prep_w<<<832, 256, 0, stream>>>(W2, W2p, 128, 6, 26);
  k_zero<<<3072, 256, 0, stream>>>(XS + 25 * plane, 786432);  // zero planes 25..27
  k_bn_partial<<<128, 256, 0, stream>>>(x, part);
  k_bn_final<<<1, 64, 0, stream>>>(part, musig);
  k_build_x0<<<8192, 256, 0, stream>>>(x, perm, musig, XS);

  // conv1: full-K fused, grid (64bx, 8by) = 512 blocks, 2 blk/CU, NT=64
  for (int k = 1; k < 25; ++k) {
    k_chebf<<<dim3(64, 8), 256, 0, stream>>>(
        XS + (size_t)(k - 1) * plane, L1h,
        XS + (size_t)(k >= 2 ? k - 2 : 0) * plane, XS + (size_t)k * plane,
        4096, 64, (k == 1) ? 1.f : 2.f, (k == 1) ? 0.f : 1.f);
  }
  // dense1 + fused pool1 -> pooled X2_0 at plane 28
  k_dense<64, 1><<<dim3(2048, 1), 256, 0, stream>>>(W1p, XS, b1, XS + 28 * plane,
                                                    4096, 4, 7, 0, 16.f, 1.f);
  // conv2: full-K fused, grid (16bx, 32by) = 512 blocks, NT=16
  auto Xp = [&](int k) { return XS + (size_t)((k == 0) ? 28 : k) * plane; };
  for (int k = 1; k < 25; ++k) {
    k_chebf<<<dim3(16, 32), 256, 0, stream>>>(
        Xp(k - 1), L2h, Xp(k >= 2 ? k - 2 : 0), Xp(k),
        1024, 16, (k == 1) ? 1.f : 2.f, (k == 1) ? 0.f : 1.f);
  }
  // dense2 + fused pool2 -> p2 (k==0 B-slice remapped to plane 28)
  k_dense<128, 2><<<dim3(512, 1), 256, 0, stream>>>(W2p, XS, b2, p2,
                                                    1024, 6, 26, 28, 1.f, 0.015625f);
  k_fc_part<<<256, 256, 0, stream>>>(p2, Wfc, partF);
  k_fc_final<<<1, 320, 0, stream>>>(partF, bfc, out);
}

// Round 17
// 1127.085 us; speedup vs baseline: 1.0650x; 1.0650x over previous
//
#include <hip/hip_runtime.h>

typedef _Float16 half8 __attribute__((ext_vector_type(8)));
typedef _Float16 half4 __attribute__((ext_vector_type(4)));
typedef float f32x4 __attribute__((ext_vector_type(4)));

__device__ __forceinline__ void gload_lds16(const void* g, void* l) {
  __builtin_amdgcn_global_load_lds((const __attribute__((address_space(1))) void*)g,
                                   (__attribute__((address_space(3))) void*)l, 16, 0, 0);
}

// ---------------- BN partial sums: grid 128 = (seg<<4 | c) ----------------
__global__ __launch_bounds__(256) void k_bn_partial(const float* __restrict__ x,
                                                    float* __restrict__ part) {
  const int c = blockIdx.x & 15;
  const int seg = blockIdx.x >> 4;
  const int t = threadIdx.x;
  float s = 0.f, s2 = 0.f;
  for (int b = 0; b < 32; ++b) {
    const float* row = x + (size_t)(b * 16 + c) * 4000 + seg * 500;
    for (int v = t; v < 500; v += 256) {
      float val = row[v];
      s += val;
      s2 += val * val;
    }
  }
#pragma unroll
  for (int off = 32; off > 0; off >>= 1) {
    s += __shfl_down(s, off);
    s2 += __shfl_down(s2, off);
  }
  __shared__ float rs_[4], rs2_[4];
  if ((t & 63) == 0) { rs_[t >> 6] = s; rs2_[t >> 6] = s2; }
  __syncthreads();
  if (t == 0) {
    part[c * 8 + seg] = rs_[0] + rs_[1] + rs_[2] + rs_[3];
    part[128 + c * 8 + seg] = rs2_[0] + rs2_[1] + rs2_[2] + rs2_[3];
  }
}

// ---------------- BN finalize ----------------
__global__ void k_bn_final(const float* __restrict__ part, float* __restrict__ musig) {
  const int c = threadIdx.x;
  if (c < 16) {
    float S = 0.f, S2 = 0.f;
#pragma unroll
    for (int seg = 0; seg < 8; ++seg) {
      S += part[c * 8 + seg];
      S2 += part[128 + c * 8 + seg];
    }
    const float inv = 1.f / 128000.f;
    float mu = S * inv;
    float var = S2 * inv - mu * mu;
    musig[c] = mu;
    musig[16 + c] = rsqrtf(var + 1e-5f);
  }
}

// ---------------- build x0 (normalized, permuted, transposed, scaled 1/16) ----------------
__global__ __launch_bounds__(256) void k_build_x0(const float* __restrict__ x,
                                                  const int* __restrict__ perm,
                                                  const float* __restrict__ musig,
                                                  _Float16* __restrict__ X0) {
  const int idx = blockIdx.x * 256 + threadIdx.x;
  const int v = idx & 4095;
  const int m = idx >> 12;
  const int b = m & 31;
  const int c = m >> 5;
  const int pv = perm[v];
  float val = 0.f;
  if (pv < 4000)
    val = (x[((size_t)(b * 16 + c)) * 4000 + pv] - musig[c]) * musig[16 + c] * 0.0625f;
  X0[idx] = (_Float16)val;
}

// ---------------- f32 -> f16 convert ----------------
__global__ __launch_bounds__(256) void k_cvt_f16(const float* __restrict__ s,
                                                 _Float16* __restrict__ d, int n) {
  const int i = (blockIdx.x * 256 + threadIdx.x) * 4;
  if (i >= n) return;
  f32x4 v = *(const f32x4*)(s + i);
  half4 h;
  h[0] = (_Float16)v[0]; h[1] = (_Float16)v[1];
  h[2] = (_Float16)v[2]; h[3] = (_Float16)v[3];
  *(half4*)(d + i) = h;
}

// ---------------- zero fill ----------------
__global__ __launch_bounds__(256) void k_zero(_Float16* __restrict__ p, int n8) {
  const int i = blockIdx.x * 256 + threadIdx.x;
  if (i < n8) *(half8*)(p + (size_t)i * 8) = half8{};
}

// ---------------- W permute+pad: Wp[f][k*CS + c] = W[f][c*25 + k] ----------------
__global__ __launch_bounds__(256) void k_prep_w(const float* __restrict__ W,
                                                _Float16* __restrict__ Wp,
                                                int F, int shiftC, int kround) {
  const int idx = blockIdx.x * 256 + threadIdx.x;
  const int CS = 1 << shiftC;
  const int KPtot = kround * CS;
  if (idx >= F * KPtot) return;
  const int f = idx / KPtot;
  const int rem = idx - f * KPtot;
  const int k = rem >> shiftC;
  const int c = rem & (CS - 1);
  float v = 0.f;
  if (k < 25) v = W[(size_t)f * (CS * 25) + c * 25 + k];
  Wp[idx] = (_Float16)v;
}

// ---------------- Chebyshev conv1 partial GEMM (R8's cheb8 — best measured) ----------------
// P[kq][m][v] = sum_{u in kq K-slice} Xprev[m][u] * L[v][u]
// Tile 128m x 256v, BK=64, 512 thr = 8 waves (2m x 4v), wave 64x64 (4x4).
// 3-buffer LDS, 2-ahead staging, fine phases, counted vmcnt(6).
__global__ __launch_bounds__(512, 1) void k_cheb8(const _Float16* __restrict__ Xprev,
                                                  const _Float16* __restrict__ Lm,
                                                  _Float16* __restrict__ P,
                                                  int V, int NT, int bxbits, int bybits) {
  __shared__ _Float16 lds[3][24576];  // [buf][A:128x64 (16KB) | B:256x64 (32KB)]
  const int t = threadIdx.x;
  const int lane = t & 63;
  const int ln = lane & 15;
  const int g = lane >> 4;
  const int g16 = g << 4;
  const int w = t >> 6;
  const int wm = w >> 2, wn = w & 3;
  const int bid = blockIdx.x;
  const int bx = bid & ((1 << bxbits) - 1);
  const int by = (bid >> bxbits) & ((1 << bybits) - 1);
  const int kq = bid >> (bxbits + bybits);
  const int v0 = bx * 256, m0 = by * 128;
  const size_t rs = (size_t)V * 2;
  const int koffB = kq * NT * 128;

  const char* Ag = (const char*)Xprev + (size_t)m0 * rs + koffB;
  const char* Bg = (const char*)Lm + (size_t)v0 * rs + koffB;

  f32x4 acc[4][4] = {};

  auto stageHalf = [&](int buf, int tt, int half) {  // 3 gload_lds / thread
    char* Lb = (char*)&lds[buf][0];
#pragma unroll
    for (int j = 0; j < 3; ++j) {
      const int idx = half * 1536 + j * 512 + t;
      if (idx < 1024) {
        const int row = idx >> 3, c8 = idx & 7;
        gload_lds16(Ag + (size_t)row * rs + tt * 128 + ((c8 ^ (row & 7)) << 4),
                    Lb + idx * 16);
      } else {
        const int bi = idx - 1024;
        const int row = bi >> 3, c8 = bi & 7;
        gload_lds16(Bg + (size_t)row * rs + tt * 128 + ((c8 ^ (row & 7)) << 4),
                    Lb + 16384 + bi * 16);
      }
    }
  };

  stageHalf(0, 0, 0); stageHalf(0, 0, 1);
  stageHalf(1, 1, 0); stageHalf(1, 1, 1);
  asm volatile("s_waitcnt vmcnt(6)" ::: "memory");
  asm volatile("s_barrier" ::: "memory");

  for (int tt = 0; tt < NT; ++tt) {
    const int cur = tt % 3;
    const int nxt = (tt + 2) % 3;
    const char* A = (const char*)&lds[cur][0];
    const char* B = A + 16384;
#pragma unroll
    for (int kk = 0; kk < 2; ++kk) {
      half8 a[4], b[4];
#pragma unroll
      for (int mi = 0; mi < 4; ++mi) {
        const int ar = wm * 64 + mi * 16 + ln;
        a[mi] = *(const half8*)(A + ar * 128 + ((kk * 64 + g16) ^ ((ar & 7) << 4)));
      }
#pragma unroll
      for (int ni = 0; ni < 4; ++ni) {
        const int br = wn * 64 + ni * 16 + ln;
        b[ni] = *(const half8*)(B + br * 128 + ((kk * 64 + g16) ^ ((br & 7) << 4)));
      }
      if (tt + 2 < NT) stageHalf(nxt, tt + 2, kk);
      if (kk == 1) {
        if (tt + 2 < NT) {
          asm volatile("s_waitcnt vmcnt(6)" ::: "memory");
        } else {
          asm volatile("s_waitcnt vmcnt(0)" ::: "memory");
        }
      }
      asm volatile("s_barrier" ::: "memory");
      asm volatile("s_waitcnt lgkmcnt(0)" ::: "memory");
      __builtin_amdgcn_sched_barrier(0);
      __builtin_amdgcn_s_setprio(1);
#pragma unroll
      for (int mi = 0; mi < 4; ++mi)
#pragma unroll
        for (int ni = 0; ni < 4; ++ni)
          acc[mi][ni] = __builtin_amdgcn_mfma_f32_16x16x32_f16(a[mi], b[ni], acc[mi][ni], 0, 0, 0);
      __builtin_amdgcn_s_setprio(0);
      asm volatile("s_barrier" ::: "memory");
    }
  }

  _Float16* Pq = P + (size_t)kq * 2097152;
#pragma unroll
  for (int mi = 0; mi < 4; ++mi) {
#pragma unroll
    for (int ni = 0; ni < 4; ++ni) {
      const int vv = v0 + wn * 64 + ni * 16 + ln;
      const int mmb = m0 + wm * 64 + mi * 16 + g * 4;
#pragma unroll
      for (int r = 0; r < 4; ++r)
        Pq[(size_t)(mmb + r) * V + vv] = (_Float16)acc[mi][ni][r];
    }
  }
}

// ---------------- reduce 4 partials: Xout = alpha*(P0+..+P3) - beta*Xm2 ----------------
__global__ __launch_bounds__(256) void k_cheb_red4(const _Float16* __restrict__ P,
                                                   const _Float16* __restrict__ Xm2,
                                                   _Float16* __restrict__ Xout,
                                                   float alpha, float beta) {
  const size_t i = ((size_t)blockIdx.x * 256 + threadIdx.x) * 8;
  float s[8] = {};
#pragma unroll
  for (int p = 0; p < 4; ++p) {
    half8 v = *(const half8*)(P + (size_t)p * 2097152 + i);
#pragma unroll
    for (int j = 0; j < 8; ++j) s[j] += (float)v[j];
  }
  half8 xm2 = {};
  if (beta != 0.f) xm2 = *(const half8*)(Xm2 + i);
  half8 o;
#pragma unroll
  for (int j = 0; j < 8; ++j) o[j] = (_Float16)(alpha * s[j] - beta * (float)xm2[j]);
  *(half8*)(Xout + i) = o;
}

// ---------------- Chebyshev conv2: fused full-K GEMM (R8, unchanged) ----------------
__global__ __launch_bounds__(256, 2) void k_cheb2(const _Float16* __restrict__ Xprev,
                                                  const _Float16* __restrict__ Lm,
                                                  const _Float16* __restrict__ Xm2,
                                                  _Float16* __restrict__ Xout,
                                                  float alpha, float beta) {
  __shared__ _Float16 lds[3][8192];  // [buf][A:64x64 (8KB) | B:64x64 (8KB)]
  const int t = threadIdx.x;
  const int lane = t & 63;
  const int ln = lane & 15;
  const int g = lane >> 4;
  const int g16 = g << 4;
  const int w = t >> 6;
  const int wm = w >> 1, wn = w & 1;
  const int bx = blockIdx.x & 15;
  const int by = blockIdx.x >> 4;
  const int v0 = bx * 64, m0 = by * 64;
  const size_t rs = 2048;  // 1024 * 2B

  const char* Ag = (const char*)Xprev + (size_t)m0 * rs;
  const char* Bg = (const char*)Lm + (size_t)v0 * rs;

  f32x4 acc[2][2] = {};

  auto stageHalf = [&](int buf, int tt, int half) {  // 2 gload_lds / thread
    const char* src = (half == 0) ? Ag : Bg;
    char* dst0 = (char*)&lds[buf][0] + half * 8192;
#pragma unroll
    for (int j = 0; j < 2; ++j) {
      const int idx = j * 256 + t;
      const int row = idx >> 3, c8 = idx & 7;
      gload_lds16(src + (size_t)row * rs + tt * 128 + ((c8 ^ (row & 7)) << 4),
                  dst0 + idx * 16);
    }
  };

  stageHalf(0, 0, 0); stageHalf(0, 0, 1);
  stageHalf(1, 1, 0); stageHalf(1, 1, 1);
  asm volatile("s_waitcnt vmcnt(4)" ::: "memory");
  asm volatile("s_barrier" ::: "memory");

  for (int tt = 0; tt < 16; ++tt) {
    const int cur = tt % 3;
    const int nxt = (tt + 2) % 3;
    const char* A = (const char*)&lds[cur][0];
    const char* B = A + 8192;
    half8 a[2][2], b[2][2];
#pragma unroll
    for (int kk = 0; kk < 2; ++kk) {
#pragma unroll
      for (int mi = 0; mi < 2; ++mi) {
        const int ar = wm * 32 + mi * 16 + ln;
        a[kk][mi] = *(const half8*)(A + ar * 128 + ((kk * 64 + g16) ^ ((ar & 7) << 4)));
      }
#pragma unroll
      for (int ni = 0; ni < 2; ++ni) {
        const int br = wn * 32 + ni * 16 + ln;
        b[kk][ni] = *(const half8*)(B + br * 128 + ((kk * 64 + g16) ^ ((br & 7) << 4)));
      }
    }
    if (tt + 2 < 16) {
      stageHalf(nxt, tt + 2, 0);
      stageHalf(nxt, tt + 2, 1);
      asm volatile("s_waitcnt vmcnt(4)" ::: "memory");
    } else {
      asm volatile("s_waitcnt vmcnt(0)" ::: "memory");
    }
    asm volatile("s_barrier" ::: "memory");
    asm volatile("s_waitcnt lgkmcnt(0)" ::: "memory");
    __builtin_amdgcn_sched_barrier(0);
    __builtin_amdgcn_s_setprio(1);
#pragma unroll
    for (int kk = 0; kk < 2; ++kk)
#pragma unroll
      for (int mi = 0; mi < 2; ++mi)
#pragma unroll
        for (int ni = 0; ni < 2; ++ni)
          acc[mi][ni] = __builtin_amdgcn_mfma_f32_16x16x32_f16(a[kk][mi], b[kk][ni],
                                                               acc[mi][ni], 0, 0, 0);
    __builtin_amdgcn_s_setprio(0);
    asm volatile("s_barrier" ::: "memory");
  }

#pragma unroll
  for (int mi = 0; mi < 2; ++mi) {
#pragma unroll
    for (int ni = 0; ni < 2; ++ni) {
      const int vv = v0 + wn * 32 + ni * 16 + ln;
      const int mmb = m0 + wm * 32 + mi * 16 + g * 4;
#pragma unroll
      for (int r = 0; r < 4; ++r) {
        const size_t idx = (size_t)(mmb + r) * 1024 + vv;
        float val = alpha * acc[mi][ni][r];
        if (beta != 0.f) val -= (float)Xm2[idx];
        Xout[idx] = (_Float16)val;
      }
    }
  }
}

// ---------------- Dense projection GEMM v2 (R15) + fused maxpool4 ----------------
template <int FT, int MODE>
__global__ __launch_bounds__(256, 2) void k_dense(const _Float16* __restrict__ Wp,
                                                  const _Float16* __restrict__ XS,
                                                  const float* __restrict__ bias,
                                                  void* __restrict__ outp,
                                                  int Vv, int shiftC, int nsteps,
                                                  int k0plane, float ascale, float bscale) {
  __shared__ _Float16 Alds[2][FT * 64];
  __shared__ _Float16 Blds[2][64 * 64];
  const int t = threadIdx.x;
  const int lane = t & 63;
  const int ln = lane & 15;
  const int g = lane >> 4;
  const int w = t >> 6;
  const int wf = w >> 1, wn = w & 1;
  const int f0w = wf * (FT / 2);
  const int n0w = wn * 32;
  const int n0 = blockIdx.x * 64;
  const int b = n0 / Vv;
  const int vb = n0 % Vv;
  const int Kp = nsteps * 64;
  const int cmask = (1 << shiftC) - 1;
  const size_t plane = 2097152;
  constexpr int NM = FT / 32;

  f32x4 acc[NM][2] = {};

  auto stageA = [&](int buf, int s) {
    const int q0 = s * 64;
    char* A = (char*)&Alds[buf][0];
#pragma unroll
    for (int j = 0; j < FT / 32; ++j) {
      const int ch = j * 256 + t;
      const int f = ch >> 3, c8 = ch & 7;
      gload_lds16((const char*)Wp + ((size_t)f * Kp + q0) * 2 + ((c8 ^ (f & 7)) << 4),
                  A + ch * 16);
    }
  };
  auto loadB = [&](int s, half8* r) {
    const int q0 = s * 64;
#pragma unroll
    for (int j = 0; j < 2; ++j) {
      const int idx = j * 256 + t;
      const int q = idx >> 3, n8 = idx & 7;
      const int qq = q0 + q;
      int k = qq >> shiftC;
      const int c = qq & cmask;
      if (k == 0) k = k0plane;
      r[j] = *(const half8*)(XS + (size_t)k * plane + (size_t)(c * 32 + b) * Vv + vb + n8 * 8);
    }
  };
  auto writeB = [&](int buf, const half8* r) {
#pragma unroll
    for (int j = 0; j < 2; ++j) {
      const int idx = j * 256 + t;
      const int q = idx >> 3, n8 = idx & 7;
#pragma unroll
      for (int e = 0; e < 8; ++e) {
        const int n = n8 * 8 + e;
        Blds[buf][n * 64 + ((((q >> 3) ^ (n >> 3) ^ (n & 7))) << 3) + (q & 7)] = r[j][e];
      }
    }
  };

  half8 rb[2];
  stageA(0, 0);
  loadB(0, rb);
  writeB(0, rb);
  asm volatile("s_waitcnt vmcnt(0)" ::: "memory");
  __syncthreads();

  for (int s = 0; s < nsteps; ++s) {
    const int cur = s & 1;
    const bool more = (s + 1 < nsteps);
    if (more) {
      stageA(cur ^ 1, s + 1);
      loadB(s + 1, rb);
    }
    const _Float16* A = &Alds[cur][0];
    const _Float16* B = &Blds[cur][0];
#pragma unroll
    for (int kk = 0; kk < 2; ++kk) {
      half8 af[NM], bf[2];
#pragma unroll
      for (int mi = 0; mi < NM; ++mi) {
        const int fr = f0w + mi * 16 + ln;
        af[mi] = *(const half8*)((const char*)A + fr * 128 +
                                 ((kk * 64 + g * 16) ^ ((fr & 7) << 4)));
      }
#pragma unroll
      for (int ni = 0; ni < 2; ++ni) {
        const int n = n0w + ni * 16 + ln;
        bf[ni] = *(const half8*)((const char*)B + n * 128 +
                                 ((((kk * 4 + g) ^ (n >> 3) ^ (n & 7))) << 4));
      }
#pragma unroll
      for (int mi = 0; mi < NM; ++mi)
#pragma unroll
        for (int ni = 0; ni < 2; ++ni)
          acc[mi][ni] = __builtin_amdgcn_mfma_f32_16x16x32_f16(af[mi], bf[ni], acc[mi][ni], 0, 0, 0);
    }
    if (more) {
      writeB(cur ^ 1, rb);
      asm volatile("s_waitcnt vmcnt(0)" ::: "memory");
      __syncthreads();
    }
  }

  const bool writer = (lane & 3) == 0;
#pragma unroll
  for (int mi = 0; mi < NM; ++mi) {
#pragma unroll
    for (int ni = 0; ni < 2; ++ni) {
#pragma unroll
      for (int r = 0; r < 4; ++r) {
        const int f = f0w + mi * 16 + g * 4 + r;
        const int v = vb + n0w + ni * 16 + ln;
        float val = fmaxf(ascale * acc[mi][ni][r] + bscale * bias[f], 0.f);
        val = fmaxf(val, __shfl_xor(val, 1));
        val = fmaxf(val, __shfl_xor(val, 2));
        if (writer) {
          if constexpr (MODE == 1) {
            _Float16* Xp = (_Float16*)outp;
            Xp[(size_t)(f * 32 + b) * 1024 + (v >> 2)] = (_Float16)(val * 0.015625f);
          } else {
            float* p2o = (float*)outp;
            p2o[(size_t)b * 32768 + f * 256 + (v >> 2)] = val;
          }
        }
      }
    }
  }
}

// ---------------- FC pass 1 ----------------
__global__ __launch_bounds__(256) void k_fc_part(const float* __restrict__ p2,
                                                 const float* __restrict__ Wfc,
                                                 float* __restrict__ partF) {
  const int b = blockIdx.x >> 3;
  const int seg = blockIdx.x & 7;
  const int t = threadIdx.x;
  const int lane = t & 63;
  const int w = t >> 6;
  const int base = seg * 4096;
  float acc[10];
#pragma unroll
  for (int o = 0; o < 10; ++o) acc[o] = 0.f;
  const float* pb = p2 + (size_t)b * 32768 + base;
  for (int i = t; i < 4096; i += 256) {
    float p = pb[i];
#pragma unroll
    for (int o = 0; o < 10; ++o) acc[o] += p * Wfc[(size_t)o * 32768 + base + i];
  }
#pragma unroll
  for (int off = 32; off > 0; off >>= 1)
#pragma unroll
    for (int o = 0; o < 10; ++o) acc[o] += __shfl_down(acc[o], off);
  __shared__ float rws[10][4];
  if (lane == 0) {
#pragma unroll
    for (int o = 0; o < 10; ++o) rws[o][w] = acc[o];
  }
  __syncthreads();
  if (t < 10) partF[blockIdx.x * 10 + t] =
      rws[t][0] + rws[t][1] + rws[t][2] + rws[t][3];
}

// ---------------- FC pass 2 ----------------
__global__ void k_fc_final(const float* __restrict__ partF,
                           const float* __restrict__ bfc,
                           float* __restrict__ out) {
  const int t = threadIdx.x;
  if (t < 320) {
    const int b = t / 10, o = t - b * 10;
    float s = 0.f;
#pragma unroll
    for (int seg = 0; seg < 8; ++seg) s += partF[(b * 8 + seg) * 10 + o];
    out[b * 10 + o] = 64.f * s + bfc[o];
  }
}

extern "C" void kernel_launch(void* const* d_in, const int* in_sizes, int n_in,
                              void* d_out, int out_size, void* d_ws, size_t ws_size,
                              hipStream_t stream) {
  (void)in_sizes; (void)n_in; (void)out_size; (void)ws_size;
  const float* x = (const float*)d_in[0];
  const int* perm = (const int*)d_in[1];
  const float* L1 = (const float*)d_in[2];
  const float* L2 = (const float*)d_in[3];
  const float* W1 = (const float*)d_in[4];
  const float* b1 = (const float*)d_in[5];
  const float* W2 = (const float*)d_in[6];
  const float* b2 = (const float*)d_in[7];
  const float* Wfc = (const float*)d_in[8];
  const float* bfc = (const float*)d_in[9];
  float* out = (float*)d_out;

  char* ws = (char*)d_ws;
  size_t off = 0;
  auto alloc = [&](size_t bytes) {
    char* p = ws + off;
    off += (bytes + 255) & ~(size_t)255;
    return p;
  };
  _Float16* L1h = (_Float16*)alloc(16777216ull * 2);
  _Float16* L2h = (_Float16*)alloc(1048576ull * 2);
  _Float16* W1p = (_Float16*)alloc(64ull * 448 * 2);
  _Float16* W2p = (_Float16*)alloc(128ull * 1664 * 2);
  float* part = (float*)alloc(256 * 4);
  float* musig = (float*)alloc(32 * 4);
  float* partF = (float*)alloc(2560 * 4);
  _Float16* XS = (_Float16*)alloc(29ull * 2097152 * 2);   // 25 states + 3 zero + 1 pooled
  _Float16* Pq = (_Float16*)alloc(4ull * 2097152 * 2);    // conv1 K-split partials
  float* p2 = (float*)alloc(32ull * 128 * 256 * 4);

  const size_t plane = 2097152;

  k_cvt_f16<<<16384, 256, 0, stream>>>(L1, L1h, 16777216);
  k_cvt_f16<<<1024, 256, 0, stream>>>(L2, L2h, 1048576);
  k_prep_w<<<112, 256, 0, stream>>>(W1, W1p, 64, 4, 28);
  k_prep_w<<<832, 256, 0, stream>>>(W2, W2p, 128, 6, 26);
  k_zero<<<3072, 256, 0, stream>>>(XS + 25 * plane, 786432);  // zero planes 25..27
  k_bn_partial<<<128, 256, 0, stream>>>(x, part);
  k_bn_final<<<1, 64, 0, stream>>>(part, musig);
  k_build_x0<<<8192, 256, 0, stream>>>(x, perm, musig, XS);

  // conv1: R8's cheb8, grid 256 = bx16 x by4 x kq4, NT=16, + red4
  for (int k = 1; k < 25; ++k) {
    k_cheb8<<<256, 512, 0, stream>>>(XS + (size_t)(k - 1) * plane, L1h, Pq, 4096, 16, 4, 2);
    k_cheb_red4<<<1024, 256, 0, stream>>>(
        Pq, XS + (size_t)(k >= 2 ? k - 2 : 0) * plane, XS + (size_t)k * plane,
        (k == 1) ? 1.f : 2.f, (k == 1) ? 0.f : 1.f);
  }
  // dense1 + fused pool1 -> pooled X2_0 at plane 28
  k_dense<64, 1><<<dim3(2048, 1), 256, 0, stream>>>(W1p, XS, b1, XS + 28 * plane,
                                                    4096, 4, 7, 0, 16.f, 1.f);
  // conv2: fused full-K, grid 512 = by32 x bx16, plane28 = X2_0
  auto Xp = [&](int k) { return XS + (size_t)((k == 0) ? 28 : k) * plane; };
  for (int k = 1; k < 25; ++k) {
    k_cheb2<<<512, 256, 0, stream>>>(
        Xp(k - 1), L2h, Xp(k >= 2 ? k - 2 : 0), Xp(k),
        (k == 1) ? 1.f : 2.f, (k == 1) ? 0.f : 1.f);
  }
  // dense2 + fused pool2 -> p2 (k==0 B-slice remapped to plane 28)
  k_dense<128, 2><<<dim3(512, 1), 256, 0, stream>>>(W2p, XS, b2, p2,
                                                    1024, 6, 26, 28, 1.f, 0.015625f);
  k_fc_part<<<256, 256, 0, stream>>>(p2, Wfc, partF);
  k_fc_final<<<1, 320, 0, stream>>>(partF, bfc, out);
}